// Round 1
// baseline (314.472 us; speedup 1.0000x reference)
//
#include <hip/hip_runtime.h>

// ---- types ----
typedef __bf16        bf16x8 __attribute__((ext_vector_type(8)));
typedef float         f32x4  __attribute__((ext_vector_type(4)));
typedef unsigned short u16x4 __attribute__((ext_vector_type(4)));
typedef unsigned short u16x8 __attribute__((ext_vector_type(8)));
typedef unsigned int  u32x4  __attribute__((ext_vector_type(4)));

#define MFMA16(a,b,c) __builtin_amdgcn_mfma_f32_16x16x32_bf16((a),(b),(c),0,0,0)

static __device__ __forceinline__ unsigned short f2bf(float f) {
  unsigned int u = __builtin_bit_cast(unsigned int, f);
  u += 0x7fffu + ((u >> 16) & 1u);          // RNE; inputs are finite
  return (unsigned short)(u >> 16);
}
static __device__ __forceinline__ bf16x8 as_bf(u32x4 v) {
  return __builtin_bit_cast(bf16x8, v);
}

// Problem constants
#define SDIM 4096      // H*W
#define CDIM 256
#define NHEAD 4
#define HDIM 64
#define NBATCH 2

// ---------------------------------------------------------------------------
// 1) cast both weight matrices fp32 -> bf16
//    wq: [768,256], wo: [256,256]
__global__ __launch_bounds__(256) void k_cast_w(const float* __restrict__ wq,
                                                const float* __restrict__ wo,
                                                unsigned short* __restrict__ wqb,
                                                unsigned short* __restrict__ wob) {
  int t = blockIdx.x * 256 + threadIdx.x;
  int i = t * 4;
  u16x4 r;
  if (i < 768 * 256) {
    float4 v = *(const float4*)(wq + i);
    r[0] = f2bf(v.x); r[1] = f2bf(v.y); r[2] = f2bf(v.z); r[3] = f2bf(v.w);
    *(u16x4*)(wqb + i) = r;
  } else {
    int j = i - 768 * 256;   // < 65536
    float4 v = *(const float4*)(wo + j);
    r[0] = f2bf(v.x); r[1] = f2bf(v.y); r[2] = f2bf(v.z); r[3] = f2bf(v.w);
    *(u16x4*)(wob + j) = r;
  }
}

// ---------------------------------------------------------------------------
// 2) GroupNorm stats: one block per (b, group); group = 16 ch x 4096 px = 65536
//    contiguous floats.  stats[bg] = (mean, rsqrt(var+eps))
__global__ __launch_bounds__(256) void k_gn_stats(const float* __restrict__ x,
                                                  float2* __restrict__ stats) {
  int bg = blockIdx.x;                 // 0..31
  int i  = threadIdx.x;
  const float* p = x + (size_t)bg * 65536;
  float s = 0.f, sq = 0.f;
#pragma unroll 4
  for (int r = 0; r < 64; ++r) {
    float4 v = *(const float4*)(p + (r * 256 + i) * 4);
    s  += v.x + v.y + v.z + v.w;
    sq += v.x * v.x + v.y * v.y + v.z * v.z + v.w * v.w;
  }
  __shared__ float rs[256], rq[256];
  rs[i] = s; rq[i] = sq;
  __syncthreads();
  for (int off = 128; off > 0; off >>= 1) {
    if (i < off) { rs[i] += rs[i + off]; rq[i] += rq[i + off]; }
    __syncthreads();
  }
  if (i == 0) {
    float mean = rs[0] * (1.f / 65536.f);
    float var  = rq[0] * (1.f / 65536.f) - mean * mean;
    stats[bg] = make_float2(mean, rsqrtf(var + 1e-5f));
  }
}

// ---------------------------------------------------------------------------
// 3) GN apply + transpose: x[b][c][s] fp32 -> xn[b][s][c] bf16
//    block = (s-chunk of 64, batch); LDS transpose, padded row stride 268.
__global__ __launch_bounds__(256) void k_gn_apply(const float* __restrict__ x,
                                                  const float2* __restrict__ stats,
                                                  const float* __restrict__ gnw,
                                                  const float* __restrict__ gnb,
                                                  unsigned short* __restrict__ xn) {
  __shared__ __attribute__((aligned(16))) unsigned short sT[64 * 268];
  int b = blockIdx.y, s0 = blockIdx.x * 64;
  int i = threadIdx.x, lane = i & 63, w = i >> 6;
#pragma unroll 4
  for (int r = 0; r < 64; ++r) {
    int c = r * 4 + w;
    int s = s0 + lane;
    float v = x[((size_t)(b * CDIM + c)) * SDIM + s];
    float2 st = stats[b * 16 + (c >> 4)];
    float nv = (v - st.x) * st.y * gnw[c] + gnb[c];
    sT[lane * 268 + c] = f2bf(nv);
  }
  __syncthreads();
#pragma unroll
  for (int r = 0; r < 16; ++r) {
    int sl = r * 4 + w;
    u16x4 v = *(const u16x4*)&sT[sl * 268 + lane * 4];
    *(u16x4*)&xn[((size_t)(b * SDIM + s0 + sl)) * CDIM + lane * 4] = v;
  }
}

// ---------------------------------------------------------------------------
// 4/6) GEMM: C[b][o][s] = sum_c W[o][c] * X[b][s][c]   (K = 256)
//    W bf16 [M][256]; X bf16 [B][4096][256].
//    PROJ=false: store bf16 to outb[b][M][4096]
//    PROJ=true : store fp32 + bias[o] + resid to outf
template <int M, bool PROJ>
__global__ __launch_bounds__(256) void k_gemm(const unsigned short* __restrict__ W,
                                              const unsigned short* __restrict__ X,
                                              unsigned short* __restrict__ outb,
                                              float* __restrict__ outf,
                                              const float* __restrict__ bias,
                                              const float* __restrict__ resid) {
  __shared__ __attribute__((aligned(16))) unsigned short sX[64 * 40]; // [s][c] pad 40
  int b = blockIdx.z, s0 = blockIdx.y * 64, o0 = blockIdx.x * 64;
  int i = threadIdx.x, lane = i & 63, w = i >> 6;
  int quad = lane >> 4, m = lane & 15;
  const unsigned short* Xb = X + ((size_t)b * SDIM + s0) * CDIM;
  int ss = i >> 2, cq = i & 3;

  f32x4 acc[4] = {};
#pragma unroll
  for (int k0 = 0; k0 < 256; k0 += 32) {
    // stage X tile [64 s][32 c] (direct copy, both [s][c])
    u32x4 xv = *(const u32x4*)(Xb + ss * CDIM + k0 + cq * 8);
    *(u32x4*)&sX[ss * 40 + cq * 8] = xv;
    __syncthreads();
    // A frag: W[o0 + w*16 + m][k0 + quad*8 .. +8)
    bf16x8 a = as_bf(*(const u32x4*)(W + (o0 + w * 16 + m) * 256 + k0 + quad * 8));
#pragma unroll
    for (int st = 0; st < 4; ++st) {
      bf16x8 bx = as_bf(*(const u32x4*)&sX[(st * 16 + m) * 40 + quad * 8]);
      acc[st] = MFMA16(a, bx, acc[st]);
    }
    __syncthreads();
  }
#pragma unroll
  for (int st = 0; st < 4; ++st) {
#pragma unroll
    for (int r = 0; r < 4; ++r) {
      int o = o0 + w * 16 + quad * 4 + r;   // D row = quad*4+reg
      int s = s0 + st * 16 + m;             // D col = lane&15
      float v = acc[st][r];
      size_t idx = ((size_t)b * M + o) * SDIM + s;
      if (PROJ) {
        outf[idx] = v + bias[o] + resid[idx];
      } else {
        outb[idx] = f2bf(v);
      }
    }
  }
}

// ---------------------------------------------------------------------------
// 5) Flash attention.  qkv[b][768][s] bf16, o-layout: h*192 + {0:q,64:k,128:v} + d.
//    Block = (q-tile 64, head, batch); wave handles 16 queries.
//    ao[b][s][c] bf16, c = h*64 + d.
__global__ __launch_bounds__(256) void k_attn(const unsigned short* __restrict__ qkv,
                                              unsigned short* __restrict__ ao) {
  __shared__ __attribute__((aligned(16))) unsigned short sK[32 * 72];   // [key][d] pad 72
  __shared__ __attribute__((aligned(16))) unsigned short sV[64 * 40];   // [d][key] pad 40
  __shared__ __attribute__((aligned(16))) unsigned short sP[4][16 * 40];// per-wave [q][key]
  int b = blockIdx.z, h = blockIdx.y, q0 = blockIdx.x * 64;
  int i = threadIdx.x, lane = i & 63, w = i >> 6;
  int quad = lane >> 4, m = lane & 15;
  const unsigned short* qb = qkv + ((size_t)b * 768 + h * 192) * SDIM;
  const unsigned short* kb = qb + (size_t)64 * SDIM;
  const unsigned short* vb = qb + (size_t)128 * SDIM;

  // Q A-frags (one-time, strided): A[m=lane&15][k=quad*8+j], dims ks*32..+32
  bf16x8 aq[2];
  {
    int qcol = q0 + w * 16 + m;
#pragma unroll
    for (int ks = 0; ks < 2; ++ks) {
      u16x8 t;
#pragma unroll
      for (int j = 0; j < 8; ++j)
        t[j] = qb[(size_t)(ks * 32 + quad * 8 + j) * SDIM + qcol];
      aq[ks] = __builtin_bit_cast(bf16x8, t);
    }
  }

  f32x4 oacc[4] = {};
  float mi[4], li[4];
#pragma unroll
  for (int r = 0; r < 4; ++r) { mi[r] = -1e30f; li[r] = 0.f; }

  int sd = i >> 2, kq = i & 3;   // staging map: d = sd (0..63), key-oct = kq
  for (int kt = 0; kt < SDIM; kt += 32) {
    // stage K (transposed -> [key][d]) and V (direct -> [d][key])
    {
      u32x4 k4 = *(const u32x4*)(kb + (size_t)sd * SDIM + kt + kq * 8);
      u16x8 kh = __builtin_bit_cast(u16x8, k4);
#pragma unroll
      for (int t = 0; t < 8; ++t) sK[(kq * 8 + t) * 72 + sd] = kh[t];
      u32x4 v4 = *(const u32x4*)(vb + (size_t)sd * SDIM + kt + kq * 8);
      *(u32x4*)&sV[sd * 40 + kq * 8] = v4;
    }
    __syncthreads();

    // QK^T: two 16x16 key sub-tiles, K-dim 64 = 2 MFMA steps
    f32x4 sc0 = {}, sc1 = {};
#pragma unroll
    for (int ks = 0; ks < 2; ++ks) {
      bf16x8 bk0 = as_bf(*(const u32x4*)&sK[m * 72 + ks * 32 + quad * 8]);
      bf16x8 bk1 = as_bf(*(const u32x4*)&sK[(16 + m) * 72 + ks * 32 + quad * 8]);
      sc0 = MFMA16(aq[ks], bk0, sc0);
      sc1 = MFMA16(aq[ks], bk1, sc1);
    }

    // online softmax (rows = quad*4+r, cols = m within each sub-tile)
    float alpha[4];
#pragma unroll
    for (int r = 0; r < 4; ++r) {
      float v0 = sc0[r] * 0.0625f;     // scale = 1/sqrt(C) = 1/16
      float v1 = sc1[r] * 0.0625f;
      float mx = fmaxf(v0, v1);
      mx = fmaxf(mx, __shfl_xor(mx, 1));
      mx = fmaxf(mx, __shfl_xor(mx, 2));
      mx = fmaxf(mx, __shfl_xor(mx, 4));
      mx = fmaxf(mx, __shfl_xor(mx, 8));
      float mn = fmaxf(mi[r], mx);
      float al = __expf(mi[r] - mn);
      float p0 = __expf(v0 - mn), p1 = __expf(v1 - mn);
      float sm = p0 + p1;
      sm += __shfl_xor(sm, 1);
      sm += __shfl_xor(sm, 2);
      sm += __shfl_xor(sm, 4);
      sm += __shfl_xor(sm, 8);
      li[r] = li[r] * al + sm;
      mi[r] = mn;
      alpha[r] = al;
      int row = quad * 4 + r;
      sP[w][row * 40 + m]      = f2bf(p0);
      sP[w][row * 40 + 16 + m] = f2bf(p1);
    }
#pragma unroll
    for (int dt = 0; dt < 4; ++dt)
#pragma unroll
      for (int r = 0; r < 4; ++r) oacc[dt][r] *= alpha[r];

    // P (A-layout via LDS) x V
    bf16x8 ap = as_bf(*(const u32x4*)&sP[w][m * 40 + quad * 8]);
#pragma unroll
    for (int dt = 0; dt < 4; ++dt) {
      bf16x8 bv = as_bf(*(const u32x4*)&sV[(dt * 16 + m) * 40 + quad * 8]);
      oacc[dt] = MFMA16(ap, bv, oacc[dt]);
    }
    __syncthreads();
  }

  float inv[4];
#pragma unroll
  for (int r = 0; r < 4; ++r) inv[r] = 1.f / li[r];
#pragma unroll
  for (int dt = 0; dt < 4; ++dt)
#pragma unroll
    for (int r = 0; r < 4; ++r) {
      int q  = q0 + w * 16 + quad * 4 + r;
      int ch = h * HDIM + dt * 16 + m;
      ao[((size_t)b * SDIM + q) * CDIM + ch] = f2bf(oacc[dt][r] * inv[r]);
    }
}

// ---------------------------------------------------------------------------
extern "C" void kernel_launch(void* const* d_in, const int* in_sizes, int n_in,
                              void* d_out, int out_size, void* d_ws, size_t ws_size,
                              hipStream_t stream) {
  const float* input = (const float*)d_in[0];
  const float* gnw   = (const float*)d_in[1];
  const float* gnb   = (const float*)d_in[2];
  const float* wq    = (const float*)d_in[3];
  const float* wo    = (const float*)d_in[4];
  const float* ob    = (const float*)d_in[5];
  float* out = (float*)d_out;

  char* ws = (char*)d_ws;
  unsigned short* xn   = (unsigned short*)(ws);                          // 4 MB  [b][s][c]
  unsigned short* qkvb = (unsigned short*)(ws + (4ull  << 20));          // 12 MB [b][768][s]
  unsigned short* ao   = (unsigned short*)(ws + (16ull << 20));          // 4 MB  [b][s][c]
  unsigned short* wqb  = (unsigned short*)(ws + (20ull << 20));          // 384 KB
  unsigned short* wob  = (unsigned short*)(ws + (20ull << 20) + (1u << 19)); // 128 KB
  float2* stats        = (float2*)(ws + (21ull << 20));                  // 256 B

  k_cast_w<<<256, 256, 0, stream>>>(wq, wo, wqb, wob);
  k_gn_stats<<<32, 256, 0, stream>>>(input, stats);
  k_gn_apply<<<dim3(64, NBATCH), 256, 0, stream>>>(input, stats, gnw, gnb, xn);
  k_gemm<768, false><<<dim3(12, 64, NBATCH), 256, 0, stream>>>(wqb, xn, qkvb, nullptr, nullptr, nullptr);
  k_attn<<<dim3(64, NHEAD, NBATCH), 256, 0, stream>>>(qkvb, ao);
  k_gemm<256, true><<<dim3(4, 64, NBATCH), 256, 0, stream>>>(wob, ao, nullptr, out, ob, input);
}

// Round 2
// 171.774 us; speedup vs baseline: 1.8307x; 1.8307x over previous
//
#include <hip/hip_runtime.h>

// ---- types ----
typedef __bf16        bf16x8 __attribute__((ext_vector_type(8)));
typedef float         f32x4  __attribute__((ext_vector_type(4)));
typedef unsigned short u16x4 __attribute__((ext_vector_type(4)));
typedef unsigned int  u32x4  __attribute__((ext_vector_type(4)));

#define MFMA16(a,b,c) __builtin_amdgcn_mfma_f32_16x16x32_bf16((a),(b),(c),0,0,0)

static __device__ __forceinline__ unsigned short f2bf(float f) {
  unsigned int u = __builtin_bit_cast(unsigned int, f);
  u += 0x7fffu + ((u >> 16) & 1u);          // RNE; inputs are finite
  return (unsigned short)(u >> 16);
}
// pack 2 floats -> bf16x2 dword, round-half-up via +0x8000 then byte-perm
static __device__ __forceinline__ unsigned int pk2(float a, float b) {
  unsigned int ua = __builtin_bit_cast(unsigned int, a) + 0x8000u;
  unsigned int ub = __builtin_bit_cast(unsigned int, b) + 0x8000u;
  return __builtin_amdgcn_perm(ub, ua, 0x07060302u);  // {ub.hi16, ua.hi16}
}
static __device__ __forceinline__ unsigned int pk2rne(float a, float b) {
  return (unsigned int)f2bf(a) | ((unsigned int)f2bf(b) << 16);
}
static __device__ __forceinline__ bf16x8 as_bf(u32x4 v) {
  return __builtin_bit_cast(bf16x8, v);
}

// Problem constants
#define SDIM 4096      // H*W
#define CDIM 256
#define NHEAD 4
#define HDIM 64
#define NBATCH 2

// ---------------------------------------------------------------------------
// 1) cast both weight matrices fp32 -> bf16  (wq: [768,256], wo: [256,256])
__global__ __launch_bounds__(256) void k_cast_w(const float* __restrict__ wq,
                                                const float* __restrict__ wo,
                                                unsigned short* __restrict__ wqb,
                                                unsigned short* __restrict__ wob) {
  int t = blockIdx.x * 256 + threadIdx.x;
  int i = t * 4;
  u16x4 r;
  if (i < 768 * 256) {
    float4 v = *(const float4*)(wq + i);
    r[0] = f2bf(v.x); r[1] = f2bf(v.y); r[2] = f2bf(v.z); r[3] = f2bf(v.w);
    *(u16x4*)(wqb + i) = r;
  } else {
    int j = i - 768 * 256;
    float4 v = *(const float4*)(wo + j);
    r[0] = f2bf(v.x); r[1] = f2bf(v.y); r[2] = f2bf(v.z); r[3] = f2bf(v.w);
    *(u16x4*)(wob + j) = r;
  }
}

// ---------------------------------------------------------------------------
// 2) GroupNorm stats: one block per (b, group) = 16ch x 4096px contiguous
__global__ __launch_bounds__(256) void k_gn_stats(const float* __restrict__ x,
                                                  float2* __restrict__ stats) {
  int bg = blockIdx.x;
  int i  = threadIdx.x;
  const float* p = x + (size_t)bg * 65536;
  float s = 0.f, sq = 0.f;
#pragma unroll 4
  for (int r = 0; r < 64; ++r) {
    float4 v = *(const float4*)(p + (r * 256 + i) * 4);
    s  += v.x + v.y + v.z + v.w;
    sq += v.x * v.x + v.y * v.y + v.z * v.z + v.w * v.w;
  }
  __shared__ float rs[256], rq[256];
  rs[i] = s; rq[i] = sq;
  __syncthreads();
  for (int off = 128; off > 0; off >>= 1) {
    if (i < off) { rs[i] += rs[i + off]; rq[i] += rq[i + off]; }
    __syncthreads();
  }
  if (i == 0) {
    float mean = rs[0] * (1.f / 65536.f);
    float var  = rq[0] * (1.f / 65536.f) - mean * mean;
    stats[bg] = make_float2(mean, rsqrtf(var + 1e-5f));
  }
}

// ---------------------------------------------------------------------------
// 3) GN apply + transpose: x[b][c][s] fp32 -> xn[b][s][c] bf16
__global__ __launch_bounds__(256) void k_gn_apply(const float* __restrict__ x,
                                                  const float2* __restrict__ stats,
                                                  const float* __restrict__ gnw,
                                                  const float* __restrict__ gnb,
                                                  unsigned short* __restrict__ xn) {
  __shared__ __attribute__((aligned(16))) unsigned short sT[64 * 268];
  int b = blockIdx.y, s0 = blockIdx.x * 64;
  int i = threadIdx.x, lane = i & 63, w = i >> 6;
#pragma unroll 4
  for (int r = 0; r < 64; ++r) {
    int c = r * 4 + w;
    int s = s0 + lane;
    float v = x[((size_t)(b * CDIM + c)) * SDIM + s];
    float2 st = stats[b * 16 + (c >> 4)];
    float nv = (v - st.x) * st.y * gnw[c] + gnb[c];
    sT[lane * 268 + c] = f2bf(nv);
  }
  __syncthreads();
#pragma unroll
  for (int r = 0; r < 16; ++r) {
    int sl = r * 4 + w;
    u16x4 v = *(const u16x4*)&sT[sl * 268 + lane * 4];
    *(u16x4*)&xn[((size_t)(b * SDIM + s0 + sl)) * CDIM + lane * 4] = v;
  }
}

// ---------------------------------------------------------------------------
// 4/6) GEMM: C[o][s] = sum_c W[o][c] * X[b][s][c]   (K = 256)
//  MODE 0 (QKV): blockIdx.x selects a 64-row section, cycling Q/K/V per head.
//    Q -> Qt[b][h][s][d] bf16, pre-scaled by log2(e)/16
//    K -> Kt[b][h][s][d] bf16
//    V -> Vb[b][h][d][s] bf16
//  MODE 1 (proj): fp32 + bias + residual -> outf[b][o][s]
template <int M, int MODE>
__global__ __launch_bounds__(256) void k_gemm(const unsigned short* __restrict__ W,
                                              const unsigned short* __restrict__ X,
                                              unsigned short* __restrict__ outQ,
                                              unsigned short* __restrict__ outK,
                                              unsigned short* __restrict__ outV,
                                              float* __restrict__ outf,
                                              const float* __restrict__ bias,
                                              const float* __restrict__ resid) {
  __shared__ __attribute__((aligned(16))) unsigned short sX[64 * 40]; // [s][c] pad 40
  int b = blockIdx.z, s0 = blockIdx.y * 64, o0 = blockIdx.x * 64;
  int i = threadIdx.x, lane = i & 63, w = i >> 6;
  int quad = lane >> 4, m = lane & 15;
  const unsigned short* Xb = X + ((size_t)b * SDIM + s0) * CDIM;
  int ss = i >> 2, cq = i & 3;

  f32x4 acc[4] = {};
#pragma unroll
  for (int k0 = 0; k0 < 256; k0 += 32) {
    u32x4 xv = *(const u32x4*)(Xb + ss * CDIM + k0 + cq * 8);
    *(u32x4*)&sX[ss * 40 + cq * 8] = xv;
    __syncthreads();
    bf16x8 a = as_bf(*(const u32x4*)(W + (o0 + w * 16 + m) * 256 + k0 + quad * 8));
#pragma unroll
    for (int st = 0; st < 4; ++st) {
      bf16x8 bx = as_bf(*(const u32x4*)&sX[(st * 16 + m) * 40 + quad * 8]);
      acc[st] = MFMA16(a, bx, acc[st]);
    }
    __syncthreads();
  }
  if (MODE == 1) {
#pragma unroll
    for (int st = 0; st < 4; ++st)
#pragma unroll
      for (int r = 0; r < 4; ++r) {
        int o = o0 + w * 16 + quad * 4 + r;
        int s = s0 + st * 16 + m;
        size_t idx = ((size_t)b * M + o) * SDIM + s;
        outf[idx] = acc[st][r] + bias[o] + resid[idx];
      }
  } else {
    int sec = (o0 >> 6) % 3;             // 0=Q, 1=K, 2=V
    int h   = o0 / 192;
    int bh  = b * NHEAD + h;
    if (sec == 2) {
#pragma unroll
      for (int st = 0; st < 4; ++st)
#pragma unroll
        for (int r = 0; r < 4; ++r) {
          int d = w * 16 + quad * 4 + r;
          int s = s0 + st * 16 + m;
          outV[((size_t)bh * HDIM + d) * SDIM + s] = f2bf(acc[st][r]);
        }
    } else {
      unsigned short* dst = (sec == 0) ? outQ : outK;
      float qs = (sec == 0) ? 0.09016844f : 1.0f;   // log2(e)/16 folded into Q
#pragma unroll
      for (int st = 0; st < 4; ++st) {
        int s = s0 + st * 16 + m;
        size_t base = ((size_t)bh * SDIM + s) * HDIM + w * 16 + quad * 4;
        *(unsigned int*)(dst + base)     = pk2rne(acc[st][0] * qs, acc[st][1] * qs);
        *(unsigned int*)(dst + base + 2) = pk2rne(acc[st][2] * qs, acc[st][3] * qs);
      }
    }
  }
}

// ---------------------------------------------------------------------------
// 5) Flash attention, S^T orientation, fixed-max softmax, key-split waves.
//    Block = (64-query tile, head, batch), 4 waves; wave w owns keys
//    [w*1024, (w+1)*1024). No __syncthreads in the main loop.
//    Qt/Kt: [bh][s][64] (Q pre-scaled by log2e/16), Vb: [bh][64][s].
//    Scores come out as S^T[key][q]; P round-trips a tiny per-wave LDS
//    region (2 ds_write_b64 + 1 ds_read_b128 per q-subtile) into B-layout.
__global__ __launch_bounds__(256, 2) void k_attn(const unsigned short* __restrict__ Qt,
                                                 const unsigned short* __restrict__ Kt,
                                                 const unsigned short* __restrict__ Vb,
                                                 unsigned short* __restrict__ ao) {
  __shared__ __attribute__((aligned(16))) char smem[20480];  // P: 4 waves x 4 qt x 1280B; reused as obuf
  __shared__ float libuf[4][64];
  int b = blockIdx.z, h = blockIdx.y, q0 = blockIdx.x * 64;
  int bh = b * NHEAD + h;
  int i = threadIdx.x, lane = i & 63, w = i >> 6;
  int quad = lane >> 4, m = lane & 15;

  const unsigned short* Qr = Qt + ((size_t)bh * SDIM + q0 + m) * HDIM + quad * 8;
  const unsigned short* Kr = Kt + ((size_t)bh * SDIM + m) * HDIM + quad * 8;
  const unsigned short* Vr = Vb + ((size_t)bh * HDIM + m) * SDIM + quad * 8;
  char* Pw = smem + w * 5120;

  // Q B-frags (held for whole kernel): q = qt*16+m, d = ks*32 + quad*8 + j
  bf16x8 bq[4][2];
#pragma unroll
  for (int qt = 0; qt < 4; ++qt)
#pragma unroll
    for (int ks = 0; ks < 2; ++ks)
      bq[qt][ks] = as_bf(*(const u32x4*)(Qr + qt * 16 * HDIM + ks * 32));

  f32x4 oacc[4][4] = {};          // [qt][dt]: O^T[dout=dt*16+quad*4+r][q=qt*16+m]
  float li[4] = {0.f, 0.f, 0.f, 0.f};

  int kbase = w * (SDIM / 4);
  for (int kt0 = 0; kt0 < SDIM / 4; kt0 += 32) {
    int kt = kbase + kt0;
    // K A-frags: key = kt + ky*16 + m, d = ks*32 + quad*8 + j
    bf16x8 ak[2][2];
#pragma unroll
    for (int ky = 0; ky < 2; ++ky)
#pragma unroll
      for (int ks = 0; ks < 2; ++ks)
        ak[ky][ks] = as_bf(*(const u32x4*)(Kr + (size_t)(kt + ky * 16) * HDIM + ks * 32));
    // V A-frags: dout = dt*16 + m, key = kt + quad*8 + j
    bf16x8 av[4];
#pragma unroll
    for (int dt = 0; dt < 4; ++dt)
      av[dt] = as_bf(*(const u32x4*)(Vr + (size_t)dt * 16 * SDIM + kt));

    // QK^T (S^T) + softmax + pack + LDS write, per q-subtile
#pragma unroll
    for (int qt = 0; qt < 4; ++qt) {
      f32x4 sc0 = {-18.f, -18.f, -18.f, -18.f};   // fixed-max shift folded into C init
      f32x4 sc1 = sc0;
      sc0 = MFMA16(ak[0][0], bq[qt][0], sc0);
      sc0 = MFMA16(ak[0][1], bq[qt][1], sc0);
      sc1 = MFMA16(ak[1][0], bq[qt][0], sc1);
      sc1 = MFMA16(ak[1][1], bq[qt][1], sc1);
      float p[8];
#pragma unroll
      for (int r = 0; r < 4; ++r) {
        p[r]     = __builtin_amdgcn_exp2f(sc0[r]);
        p[4 + r] = __builtin_amdgcn_exp2f(sc1[r]);
      }
      li[qt] += ((p[0] + p[1]) + (p[2] + p[3])) + ((p[4] + p[5]) + (p[6] + p[7]));
      // lane (quad=qs, m) holds keys {4qs..4qs+3} (ky0) and {16+4qs..} (ky1)
      // row m dword j must hold keys {2j, 2j+1}
      char* pb = Pw + qt * 1280 + m * 80 + quad * 8;
      *(uint2*)(pb)      = make_uint2(pk2(p[0], p[1]), pk2(p[2], p[3]));
      *(uint2*)(pb + 32) = make_uint2(pk2(p[4], p[5]), pk2(p[6], p[7]));
    }
    // P B-frags + PV
#pragma unroll
    for (int qt = 0; qt < 4; ++qt) {
      bf16x8 bp = *(bf16x8*)(Pw + qt * 1280 + m * 80 + quad * 16);
#pragma unroll
      for (int dt = 0; dt < 4; ++dt)
        oacc[qt][dt] = MFMA16(av[dt], bp, oacc[qt][dt]);
    }
  }

  // reduce li across the 4 quads (they hold disjoint key subsets for q=m)
#pragma unroll
  for (int qt = 0; qt < 4; ++qt) {
    li[qt] += __shfl_xor(li[qt], 16);
    li[qt] += __shfl_xor(li[qt], 32);
  }
  if (quad == 0) {
#pragma unroll
    for (int qt = 0; qt < 4; ++qt) libuf[w][qt * 16 + m] = li[qt];
  }
  __syncthreads();   // all waves done with P regions; smem becomes obuf

  float* obuf = (float*)smem;   // [64 q][68 stride] fp32
#pragma unroll
  for (int pw = 0; pw < 4; ++pw) {
    if (w == pw) {
#pragma unroll
      for (int qt = 0; qt < 4; ++qt)
#pragma unroll
        for (int dt = 0; dt < 4; ++dt) {
          float* dst = obuf + (qt * 16 + m) * 68 + dt * 16 + quad * 4;
          f32x4 v = oacc[qt][dt];
          if (pw > 0) v = v + *(f32x4*)dst;
          *(f32x4*)dst = v;
        }
    }
    __syncthreads();
  }

  // normalize + store: thread i -> q = i&63, d-group = i>>6 (16 douts)
  {
    int q = i & 63, dg = i >> 6;
    float lsum = libuf[0][q] + libuf[1][q] + libuf[2][q] + libuf[3][q];
    float linv = 1.f / lsum;
    const float* src = obuf + q * 68 + dg * 16;
    unsigned int dw[8];
#pragma unroll
    for (int e = 0; e < 8; ++e) dw[e] = pk2rne(src[2 * e] * linv, src[2 * e + 1] * linv);
    unsigned short* dst = ao + ((size_t)b * SDIM + q0 + q) * CDIM + h * HDIM + dg * 16;
    *(u32x4*)(dst)     = u32x4{dw[0], dw[1], dw[2], dw[3]};
    *(u32x4*)(dst + 8) = u32x4{dw[4], dw[5], dw[6], dw[7]};
  }
}

// ---------------------------------------------------------------------------
extern "C" void kernel_launch(void* const* d_in, const int* in_sizes, int n_in,
                              void* d_out, int out_size, void* d_ws, size_t ws_size,
                              hipStream_t stream) {
  const float* input = (const float*)d_in[0];
  const float* gnw   = (const float*)d_in[1];
  const float* gnb   = (const float*)d_in[2];
  const float* wq    = (const float*)d_in[3];
  const float* wo    = (const float*)d_in[4];
  const float* ob    = (const float*)d_in[5];
  float* out = (float*)d_out;

  char* ws = (char*)d_ws;
  unsigned short* xn  = (unsigned short*)(ws);                    // 4 MB  [b][s][c]
  unsigned short* Qt  = (unsigned short*)(ws + (4ull  << 20));    // 4 MB  [bh][s][d]
  unsigned short* Kt  = (unsigned short*)(ws + (8ull  << 20));    // 4 MB  [bh][s][d]
  unsigned short* Vb  = (unsigned short*)(ws + (12ull << 20));    // 4 MB  [bh][d][s]
  unsigned short* ao  = (unsigned short*)(ws + (16ull << 20));    // 4 MB  [b][s][c]
  unsigned short* wqb = (unsigned short*)(ws + (20ull << 20));    // 384 KB
  unsigned short* wob = (unsigned short*)(ws + (20ull << 20) + (1u << 19)); // 128 KB
  float2* stats       = (float2*)(ws + (21ull << 20));            // 256 B

  k_cast_w<<<256, 256, 0, stream>>>(wq, wo, wqb, wob);
  k_gn_stats<<<32, 256, 0, stream>>>(input, stats);
  k_gn_apply<<<dim3(64, NBATCH), 256, 0, stream>>>(input, stats, gnw, gnb, xn);
  k_gemm<768, 0><<<dim3(12, 64, NBATCH), 256, 0, stream>>>(wqb, xn, Qt, Kt, Vb, nullptr, nullptr, nullptr);
  k_attn<<<dim3(64, NHEAD, NBATCH), 256, 0, stream>>>(Qt, Kt, Vb, ao);
  k_gemm<256, 1><<<dim3(4, 64, NBATCH), 256, 0, stream>>>(wob, ao, nullptr, nullptr, nullptr, out, ob, input);
}

// Round 3
// 159.391 us; speedup vs baseline: 1.9730x; 1.0777x over previous
//
#include <hip/hip_runtime.h>

// ---- types ----
typedef __bf16        bf16x8 __attribute__((ext_vector_type(8)));
typedef float         f32x4  __attribute__((ext_vector_type(4)));
typedef unsigned short u16x4 __attribute__((ext_vector_type(4)));
typedef unsigned short u16x8 __attribute__((ext_vector_type(8)));
typedef unsigned int  u32x4  __attribute__((ext_vector_type(4)));

#define MFMA16(a,b,c) __builtin_amdgcn_mfma_f32_16x16x32_bf16((a),(b),(c),0,0,0)

static __device__ __forceinline__ unsigned short f2bf(float f) {
  unsigned int u = __builtin_bit_cast(unsigned int, f);
  u += 0x7fffu + ((u >> 16) & 1u);          // RNE; inputs are finite
  return (unsigned short)(u >> 16);
}
// pack 2 floats -> bf16x2 dword, round-half-up via +0x8000 then byte-perm
static __device__ __forceinline__ unsigned int pk2(float a, float b) {
  unsigned int ua = __builtin_bit_cast(unsigned int, a) + 0x8000u;
  unsigned int ub = __builtin_bit_cast(unsigned int, b) + 0x8000u;
  return __builtin_amdgcn_perm(ub, ua, 0x07060302u);
}
static __device__ __forceinline__ unsigned int pk2rne(float a, float b) {
  return (unsigned int)f2bf(a) | ((unsigned int)f2bf(b) << 16);
}
static __device__ __forceinline__ bf16x8 as_bf(u32x4 v) {
  return __builtin_bit_cast(bf16x8, v);
}
static __device__ __forceinline__ float bf2f(unsigned short u) {
  return __builtin_bit_cast(float, ((unsigned int)u) << 16);
}
// async 16B-per-lane global->LDS DMA; LDS image = base + lane*16
static __device__ __forceinline__ void dma16(const unsigned short* g, unsigned short* l) {
  __builtin_amdgcn_global_load_lds((const __attribute__((address_space(1))) unsigned int*)g,
                                   (__attribute__((address_space(3))) unsigned int*)l, 16, 0, 0);
}

// Problem constants
#define SDIM 4096
#define CDIM 256
#define NHEAD 4
#define HDIM 64
#define NBATCH 2
#define KSPLIT 4

// ---------------------------------------------------------------------------
// 1) merged prep: blocks 0..255 = GN partial stats, 256..319 = weight cast
__global__ __launch_bounds__(256) void k_prep(const float* __restrict__ x,
                                              const float* __restrict__ wq,
                                              const float* __restrict__ wo,
                                              unsigned short* __restrict__ wqb,
                                              unsigned short* __restrict__ wob,
                                              float2* __restrict__ Sp) {
  int j = blockIdx.x, i = threadIdx.x;
  if (j < 256) {
    // partial stats: bg = j>>3, sub-range (j&7)*8192 floats
    const float* p = x + (size_t)(j >> 3) * 65536 + (size_t)(j & 7) * 8192;
    float s = 0.f, sq = 0.f;
#pragma unroll
    for (int r = 0; r < 8; ++r) {
      float4 v = *(const float4*)(p + (r * 256 + i) * 4);
      s  += v.x + v.y + v.z + v.w;
      sq += v.x * v.x + v.y * v.y + v.z * v.z + v.w * v.w;
    }
    __shared__ float rs[256], rq[256];
    rs[i] = s; rq[i] = sq;
    __syncthreads();
    for (int off = 128; off > 0; off >>= 1) {
      if (i < off) { rs[i] += rs[i + off]; rq[i] += rq[i + off]; }
      __syncthreads();
    }
    if (i == 0) Sp[j] = make_float2(rs[0], rq[0]);
  } else {
    int t = (j - 256) * 256 + i;          // 0..16383, 16 floats each
    int e = t * 16;
#pragma unroll
    for (int c = 0; c < 4; ++c) {
      int idx = e + c * 4;
      const float* src = (idx < 768 * 256) ? (wq + idx) : (wo + idx - 768 * 256);
      unsigned short* dst = (idx < 768 * 256) ? (wqb + idx) : (wob + idx - 768 * 256);
      float4 v = *(const float4*)src;
      u16x4 r; r[0] = f2bf(v.x); r[1] = f2bf(v.y); r[2] = f2bf(v.z); r[3] = f2bf(v.w);
      *(u16x4*)dst = r;
    }
  }
}

// ---------------------------------------------------------------------------
// 2) GN apply + transpose: x[b][c][s] fp32 -> xn[b][s][c] bf16 (stats from Sp)
__global__ __launch_bounds__(256) void k_gn_apply(const float* __restrict__ x,
                                                  const float2* __restrict__ Sp,
                                                  const float* __restrict__ gnw,
                                                  const float* __restrict__ gnb,
                                                  unsigned short* __restrict__ xn) {
  __shared__ __attribute__((aligned(16))) unsigned short sT[64 * 268];
  __shared__ float2 sStat[16];
  int b = blockIdx.y, s0 = blockIdx.x * 64;
  int i = threadIdx.x, lane = i & 63, w = i >> 6;
  if (i < 16) {
    float s = 0.f, sq = 0.f;
#pragma unroll
    for (int u = 0; u < 8; ++u) {
      float2 v = Sp[(b * 16 + i) * 8 + u];
      s += v.x; sq += v.y;
    }
    float mean = s * (1.f / 65536.f);
    float var  = sq * (1.f / 65536.f) - mean * mean;
    sStat[i] = make_float2(mean, rsqrtf(var + 1e-5f));
  }
  __syncthreads();
#pragma unroll 4
  for (int r = 0; r < 64; ++r) {
    int c = r * 4 + w;
    float v = x[((size_t)(b * CDIM + c)) * SDIM + s0 + lane];
    float2 st = sStat[c >> 4];
    float nv = (v - st.x) * st.y * gnw[c] + gnb[c];
    sT[lane * 268 + c] = f2bf(nv);
  }
  __syncthreads();
#pragma unroll
  for (int r = 0; r < 16; ++r) {
    int sl = r * 4 + w;
    u16x4 v = *(const u16x4*)&sT[sl * 268 + lane * 4];
    *(u16x4*)&xn[((size_t)(b * SDIM + s0 + sl)) * CDIM + lane * 4] = v;
  }
}

// ---------------------------------------------------------------------------
// 3/5) GEMM: D[o][s] = sum_c W[o][c] * X[b][s][c]  (K=256)
//  MODE 0 (QKV): epilogue repacks into MFMA frag-linear layouts:
//    Qf/Kf[bh][tile16 = s/16][ks = d/32][lane][8]  (B/A-frag: m'=s%16, k=quad'*8+j)
//      Q pre-scaled by log2(e)/16
//    Vf[bh][kt32 = s/32][dt = d/16][lane][8]       (A-frag: m'=d%16, k=quad'*8+j)
//  MODE 1 (proj): fp32 + bias + residual -> outf[b][o][s]
template <int M, int MODE>
__global__ __launch_bounds__(256) void k_gemm(const unsigned short* __restrict__ W,
                                              const unsigned short* __restrict__ X,
                                              unsigned short* __restrict__ Qf,
                                              unsigned short* __restrict__ Kf,
                                              unsigned short* __restrict__ Vf,
                                              float* __restrict__ outf,
                                              const float* __restrict__ bias,
                                              const float* __restrict__ resid) {
  __shared__ __attribute__((aligned(16))) unsigned short sX[64 * 40];
  __shared__ __attribute__((aligned(16))) unsigned short sB[64 * 68];  // bounce [s][o]
  int b = blockIdx.z, s0 = blockIdx.y * 64, o0 = blockIdx.x * 64;
  int i = threadIdx.x, lane = i & 63, w = i >> 6;
  int quad = lane >> 4, m = lane & 15;
  const unsigned short* Xb = X + ((size_t)b * SDIM + s0) * CDIM;
  int ss = i >> 2, cq = i & 3;

  f32x4 acc[4] = {};
#pragma unroll
  for (int k0 = 0; k0 < 256; k0 += 32) {
    u32x4 xv = *(const u32x4*)(Xb + ss * CDIM + k0 + cq * 8);
    *(u32x4*)&sX[ss * 40 + cq * 8] = xv;
    __syncthreads();
    bf16x8 a = as_bf(*(const u32x4*)(W + (o0 + w * 16 + m) * 256 + k0 + quad * 8));
#pragma unroll
    for (int st = 0; st < 4; ++st) {
      bf16x8 bx = as_bf(*(const u32x4*)&sX[(st * 16 + m) * 40 + quad * 8]);
      acc[st] = MFMA16(a, bx, acc[st]);
    }
    __syncthreads();
  }
  if (MODE == 1) {
#pragma unroll
    for (int st = 0; st < 4; ++st)
#pragma unroll
      for (int r = 0; r < 4; ++r) {
        int o = o0 + w * 16 + quad * 4 + r;
        int s = s0 + st * 16 + m;
        size_t idx = ((size_t)b * M + o) * SDIM + s;
        outf[idx] = acc[st][r] + bias[o] + resid[idx];
      }
  } else {
    int sec = (o0 >> 6) % 3;             // 0=Q, 1=K, 2=V
    int h   = o0 / 192;
    int bh  = b * NHEAD + h;
    float qs = (sec == 0) ? 0.09016844f : 1.0f;   // log2(e)/16 folded into Q
    // bounce D[s][o] into LDS (bf16, stride 68)
#pragma unroll
    for (int st = 0; st < 4; ++st) {
      uint2 pk = make_uint2(pk2rne(acc[st][0] * qs, acc[st][1] * qs),
                            pk2rne(acc[st][2] * qs, acc[st][3] * qs));
      *(uint2*)&sB[(st * 16 + m) * 68 + w * 16 + quad * 4] = pk;
    }
    __syncthreads();
    int lp = i & 63, qp = lp >> 4, mp = lp & 15, t = i >> 6;
    if (sec < 2) {
      unsigned short* base = (sec == 0) ? Qf : Kf;
#pragma unroll
      for (int ks = 0; ks < 2; ++ks) {
        const unsigned short* src = &sB[(t * 16 + mp) * 68 + ks * 32 + qp * 8];
        u16x4 lo = *(const u16x4*)src;
        u16x4 hi = *(const u16x4*)(src + 4);
        unsigned short* dst = base + ((((size_t)bh * 256 + (s0 >> 4) + t) * 2 + ks) * 64 + lp) * 8;
        *(u16x4*)dst = lo;
        *(u16x4*)(dst + 4) = hi;
      }
    } else {
      int kt32l = t >> 1, dts = (t & 1) * 2;
#pragma unroll
      for (int dd = 0; dd < 2; ++dd) {
        int dt = dts + dd;
        u16x8 v;
#pragma unroll
        for (int jj = 0; jj < 8; ++jj)
          v[jj] = sB[(kt32l * 32 + qp * 8 + jj) * 68 + dt * 16 + mp];
        unsigned short* dst = Vf + ((((size_t)bh * 128 + (s0 >> 5) + kt32l) * 4 + dt) * 64 + lp) * 8;
        *(u16x8*)dst = v;
      }
    }
  }
}

// ---------------------------------------------------------------------------
// 4) Flash attention, frag-linear inputs, shared LDS tiles, key-split blocks.
//    Block = (256-q tile, bh, ksplit), 4 waves x 64q each, all waves share the
//    staged 32-key K/V tiles (double-buffered global_load_lds, 1 barrier/iter).
//    Fixed-max softmax (shift folded into C-init, Q pre-scaled by log2e/16).
//    Outputs per-split partials: Opb bf16 [ks][bh][q][64], Lp fp32 [ks][bh][q].
__global__ __launch_bounds__(256, 2) void k_attn(const unsigned short* __restrict__ Qf,
                                                 const unsigned short* __restrict__ Kf,
                                                 const unsigned short* __restrict__ Vf,
                                                 unsigned short* __restrict__ Opb,
                                                 float* __restrict__ Lp) {
  __shared__ __attribute__((aligned(16))) unsigned short sK[2][2048]; // 4 slots x 64 lanes x 8
  __shared__ __attribute__((aligned(16))) unsigned short sV[2][2048];
  __shared__ __attribute__((aligned(16))) unsigned short sP[4][64 * 40];
  int bh = blockIdx.y, kk = blockIdx.z;
  int i = threadIdx.x, lane = i & 63, w = i >> 6;
  int quad = lane >> 4, m = lane & 15;
  int qbase = blockIdx.x * 256 + w * 64;

  // Q B-frags, direct coalesced global loads (frag-linear)
  bf16x8 bq[4][2];
#pragma unroll
  for (int qt = 0; qt < 4; ++qt)
#pragma unroll
    for (int ks = 0; ks < 2; ++ks)
      bq[qt][ks] = as_bf(*(const u32x4*)(Qf +
        ((((size_t)bh * 256 + ((qbase >> 4) + qt)) * 2 + ks) * 64 + lane) * 8));

  f32x4 oacc[4][4] = {};
  float li[4] = {0.f, 0.f, 0.f, 0.f};

  // per-iter DMA: wave w stages K slot w (ky=w>>1, ks=w&1) and V slot w (dt=w)
  auto dma = [&](int it, int buf) {
    int kb16 = kk * 64 + it * 2 + (w >> 1);
    dma16(Kf + ((((size_t)bh * 256 + kb16) * 2 + (w & 1)) * 64 + lane) * 8,
          &sK[buf][w * 512]);
    int kb32 = kk * 32 + it;
    dma16(Vf + ((((size_t)bh * 128 + kb32) * 4 + w) * 64 + lane) * 8,
          &sV[buf][w * 512]);
  };
  dma(0, 0);

  for (int it = 0; it < 32; ++it) {
    int buf = it & 1;
    __syncthreads();                      // drains own DMA (vmcnt) then barrier
    if (it < 31) dma(it + 1, buf ^ 1);    // prefetch overlaps compute below

    bf16x8 ak[2][2], av[4];
#pragma unroll
    for (int ky = 0; ky < 2; ++ky)
#pragma unroll
      for (int ks = 0; ks < 2; ++ks)
        ak[ky][ks] = *(const bf16x8*)&sK[buf][((ky * 2 + ks) * 64 + lane) * 8];
#pragma unroll
    for (int dt = 0; dt < 4; ++dt)
      av[dt] = *(const bf16x8*)&sV[buf][(dt * 64 + lane) * 8];

#pragma unroll
    for (int qt = 0; qt < 4; ++qt) {
      f32x4 sc0 = {-18.f, -18.f, -18.f, -18.f};
      f32x4 sc1 = sc0;
      sc0 = MFMA16(ak[0][0], bq[qt][0], sc0);
      sc0 = MFMA16(ak[0][1], bq[qt][1], sc0);
      sc1 = MFMA16(ak[1][0], bq[qt][0], sc1);
      sc1 = MFMA16(ak[1][1], bq[qt][1], sc1);
      float p[8];
#pragma unroll
      for (int r = 0; r < 4; ++r) {
        p[r]     = __builtin_amdgcn_exp2f(sc0[r]);
        p[4 + r] = __builtin_amdgcn_exp2f(sc1[r]);
      }
      li[qt] += ((p[0] + p[1]) + (p[2] + p[3])) + ((p[4] + p[5]) + (p[6] + p[7]));
      // P rows q=qt*16+m; lane's keys: ky*16 + quad*4 + r
      int row = (qt * 16 + m) * 40;
      *(uint2*)&sP[w][row + quad * 4]      = make_uint2(pk2(p[0], p[1]), pk2(p[2], p[3]));
      *(uint2*)&sP[w][row + 16 + quad * 4] = make_uint2(pk2(p[4], p[5]), pk2(p[6], p[7]));
    }
#pragma unroll
    for (int qt = 0; qt < 4; ++qt) {
      // B-frag: q col = m, key k = quad*8+j
      bf16x8 bp = *(const bf16x8*)&sP[w][(qt * 16 + m) * 40 + quad * 8];
#pragma unroll
      for (int dt = 0; dt < 4; ++dt)
        oacc[qt][dt] = MFMA16(av[dt], bp, oacc[qt][dt]);
    }
  }

  // li: reduce across quads (disjoint keys per quad), store partials
  size_t qg = (size_t)(kk * 8 + bh) * SDIM + qbase;
#pragma unroll
  for (int qt = 0; qt < 4; ++qt) {
    li[qt] += __shfl_xor(li[qt], 16);
    li[qt] += __shfl_xor(li[qt], 32);
  }
  if (quad == 0) {
#pragma unroll
    for (int qt = 0; qt < 4; ++qt) Lp[qg + qt * 16 + m] = li[qt];
  }
#pragma unroll
  for (int qt = 0; qt < 4; ++qt)
#pragma unroll
    for (int dt = 0; dt < 4; ++dt) {
      uint2 pk = make_uint2(pk2rne(oacc[qt][dt][0], oacc[qt][dt][1]),
                            pk2rne(oacc[qt][dt][2], oacc[qt][dt][3]));
      *(uint2*)&Opb[(qg + qt * 16 + m) * 64 + dt * 16 + quad * 4] = pk;
    }
}

// ---------------------------------------------------------------------------
// 5) combine partials: ao[b][q][h*64+d] = sum_ks Opb / sum_ks Lp  (bf16)
__global__ __launch_bounds__(256) void k_combine(const unsigned short* __restrict__ Opb,
                                                 const float* __restrict__ Lp,
                                                 unsigned short* __restrict__ ao) {
  int gid = blockIdx.x * 256 + threadIdx.x;     // 131072
  int bh = gid >> 14, rem = gid & 16383, q = rem >> 2, dq = rem & 3;
  float li = 0.f, o[16];
#pragma unroll
  for (int e = 0; e < 16; ++e) o[e] = 0.f;
#pragma unroll
  for (int ks = 0; ks < KSPLIT; ++ks) {
    size_t base = (size_t)(ks * 8 + bh) * SDIM + q;
    li += Lp[base];
    const unsigned short* p = Opb + base * 64 + dq * 16;
    u16x8 a = *(const u16x8*)p, b2 = *(const u16x8*)(p + 8);
#pragma unroll
    for (int e = 0; e < 8; ++e) { o[e] += bf2f(a[e]); o[8 + e] += bf2f(b2[e]); }
  }
  float inv = 1.f / li;
  unsigned int dw[8];
#pragma unroll
  for (int e = 0; e < 8; ++e) dw[e] = pk2rne(o[2 * e] * inv, o[2 * e + 1] * inv);
  unsigned short* dst = ao + ((size_t)((bh >> 2) * SDIM + q)) * CDIM + (bh & 3) * HDIM + dq * 16;
  *(u32x4*)dst       = u32x4{dw[0], dw[1], dw[2], dw[3]};
  *(u32x4*)(dst + 8) = u32x4{dw[4], dw[5], dw[6], dw[7]};
}

// ---------------------------------------------------------------------------
extern "C" void kernel_launch(void* const* d_in, const int* in_sizes, int n_in,
                              void* d_out, int out_size, void* d_ws, size_t ws_size,
                              hipStream_t stream) {
  const float* input = (const float*)d_in[0];
  const float* gnw   = (const float*)d_in[1];
  const float* gnb   = (const float*)d_in[2];
  const float* wq    = (const float*)d_in[3];
  const float* wo    = (const float*)d_in[4];
  const float* ob    = (const float*)d_in[5];
  float* out = (float*)d_out;

  char* ws = (char*)d_ws;
  unsigned short* xn  = (unsigned short*)(ws);                    // 4 MB [b][s][c]
  unsigned short* Qf  = (unsigned short*)(ws + (4ull  << 20));    // 4 MB frag-linear
  unsigned short* Kf  = (unsigned short*)(ws + (8ull  << 20));    // 4 MB
  unsigned short* Vf  = (unsigned short*)(ws + (12ull << 20));    // 4 MB
  unsigned short* ao  = (unsigned short*)(ws + (16ull << 20));    // 4 MB [b][s][c]
  unsigned short* wqb = (unsigned short*)(ws + (20ull << 20));    // 384 KB
  unsigned short* wob = (unsigned short*)(ws + (20ull << 20) + (1u << 19)); // 128 KB
  float2* Sp          = (float2*)(ws + (21ull << 20));            // 2 KB
  float* Lp           = (float*)(ws + (21ull << 20) + (1u << 19));// 512 KB
  unsigned short* Opb = (unsigned short*)(ws + (22ull << 20));    // 16 MB

  k_prep<<<320, 256, 0, stream>>>(input, wq, wo, wqb, wob, Sp);
  k_gn_apply<<<dim3(64, NBATCH), 256, 0, stream>>>(input, Sp, gnw, gnb, xn);
  k_gemm<768, 0><<<dim3(12, 64, NBATCH), 256, 0, stream>>>(wqb, xn, Qf, Kf, Vf, nullptr, nullptr, nullptr);
  k_attn<<<dim3(16, NHEAD * NBATCH, KSPLIT), 256, 0, stream>>>(Qf, Kf, Vf, Opb, Lp);
  k_combine<<<512, 256, 0, stream>>>(Opb, Lp, ao);
  k_gemm<256, 1><<<dim3(4, 64, NBATCH), 256, 0, stream>>>(wob, ao, nullptr, nullptr, nullptr, out, ob, input);
}